// Round 1
// 542.548 us; speedup vs baseline: 1.0395x; 1.0395x over previous
//
#include <hip/hip_runtime.h>
#include <stdint.h>

using f4v = __attribute__((ext_vector_type(4))) float;
using s8v = __attribute__((ext_vector_type(8))) short;

constexpr int C_ = 128, H_ = 128, W_ = 128, HW_ = H_ * W_;
constexpr int S_ = 4;             // y-splits for k_dw
constexpr int OROWS = H_ / S_;    // 32 output rows per block
static_assert(OROWS == 32, "bias table indexing assumes 32 rows/block");

__device__ __forceinline__ unsigned f2bf(float f) {
  union { float f; unsigned u; } v; v.f = f;
  return (v.u + 0x7FFFu + ((v.u >> 16) & 1u)) >> 16;   // RTNE
}

// ---------------------------------------------------------------------------
// Kernel 1: fused depthwise branches -> add (bf16), column-sweep with circular
// register accumulators. Block = 8 channels x 32-col strip x 32 output rows.
// y-split S_=4: each block sweeps [obase-5, oend+4] clamped, emitting only
// o in [obase, oend). Garbage warmup outputs (o < obase) are zeroed at their
// would-be emit row, which also covers the old top-boundary fix.
// ws layout: [n][g=c/8][p=h*128+w][c%8] bf16 (16B per pixel-group).
// ---------------------------------------------------------------------------
__global__ __launch_bounds__(256, 4) void k_dw(
    const float* __restrict__ x,
    const float* __restrict__ w0,  const float* __restrict__ b0,
    const float* __restrict__ w01, const float* __restrict__ b01,
    const float* __restrict__ w02, const float* __restrict__ b02,
    const float* __restrict__ w11, const float* __restrict__ b11,
    const float* __restrict__ w12, const float* __restrict__ b12,
    unsigned short* __restrict__ ws)
{
  __shared__ float xs[8][16][48];            // 16-row chunk + 8-col halo each side
  __shared__ unsigned short ebuf[16][8][32]; // emit transpose buffer [row][ch][x]
  __shared__ float bias_row[8][OROWS];       // b0+b02+b12 + b01*s5(y) + b11*s11(y)

  const int t = threadIdx.x;
  const int xstrip = blockIdx.x & 3, yb = blockIdx.x >> 2;
  const int g = blockIdx.y, n = blockIdx.z;
  const int xbase = xstrip * 32;
  const int c0 = g * 8;
  const int ch = t >> 5, xl = t & 31;
  const int c = c0 + ch;

  const int obase = yb * OROWS;
  const int oend  = obase + OROWS;
  const int sbase = (obase >= 5) ? (obase - 5) : 0;
  const int lastrow = (oend + 4 <= H_ - 1) ? (oend + 4) : (H_ - 1);
  const int nrows = lastrow - sbase + 1;     // 37 (edge) or 42 (middle)
  const int nchunk = (nrows + 15) >> 4;

  // per-thread weights in registers (41 floats)
  float w0t[9], w01t[5], w02t[5], w11t[11], w12t[11];
#pragma unroll
  for (int k = 0; k < 9; ++k)  w0t[k] = w0[c * 9 + k];
#pragma unroll
  for (int k = 0; k < 5; ++k)  { w01t[k] = w01[c * 5 + k]; w02t[k] = w02[c * 5 + k]; }
#pragma unroll
  for (int k = 0; k < 11; ++k) { w11t[k] = w11[c * 11 + k]; w12t[k] = w12[c * 11 + k]; }

  // boundary-bias table for this block's 32 outputs: one entry per thread
  {
    const int cb = t >> 5, oo = t & 31;
    const int y = obase + oo, cc = c0 + cb;
    float s5 = 0.f, s11 = 0.f;
#pragma unroll
    for (int k = 0; k < 5; ++k)  if ((unsigned)(y - 2 + k) < 128u) s5  += w02[cc * 5 + k];
#pragma unroll
    for (int k = 0; k < 11; ++k) if ((unsigned)(y - 5 + k) < 128u) s11 += w12[cc * 11 + k];
    bias_row[cb][oo] = b0[cc] + b02[cc] + b12[cc] + b01[cc] * s5 + b11[cc] * s11;
  }

  float acc[16];
#pragma unroll
  for (int i = 0; i < 16; ++i) acc[i] = 0.f;

  unsigned short* wsp = ws + (size_t)(n * 16 + g) * HW_ * 8;

  for (int cidx = 0; cidx < nchunk; ++cidx) {
    const int r0g = sbase + cidx * 16;       // global row of chunk start
    const int rem_rows = nrows - cidx * 16;
    const int rlim = rem_rows < 16 ? rem_rows : 16;
    __syncthreads();
    // stage up to 16 rows x 48 cols x 8 ch (OOB / beyond-rlim -> 0), float4
#pragma unroll
    for (int i = 0; i < 6; ++i) {
      int id = i * 256 + t;
      int chs = id / 192;
      int rem = id - chs * 192;
      int rs = rem / 12;
      int c4 = rem - rs * 12;
      int gx = xbase - 8 + c4 * 4;
      float4 v = make_float4(0.f, 0.f, 0.f, 0.f);
      if ((unsigned)gx < 128u && rs < rlim)
        v = *(const float4*)(x + (size_t)((n * C_ + c0 + chs) * H_ + r0g + rs) * W_ + gx);
      *(float4*)&xs[chs][rs][c4 * 4] = v;
    }
    __syncthreads();
#pragma unroll
    for (int rr = 0; rr < 16; ++rr) {
      if (rr < rlim) {
        float win[11];
#pragma unroll
        for (int k = 0; k < 11; ++k) win[k] = xs[ch][rr][xl + 3 + k];
        // horizontal filters share the window
        float h11 = w11t[0] * win[0];
#pragma unroll
        for (int k = 1; k < 11; ++k) h11 += w11t[k] * win[k];
        float h5 = w01t[0] * win[3];
#pragma unroll
        for (int k = 1; k < 5; ++k) h5 += w01t[k] * win[3 + k];
        float r0v = w0t[0] * win[4] + w0t[1] * win[5] + w0t[2] * win[6];
        float r1v = w0t[3] * win[4] + w0t[4] * win[5] + w0t[5] * win[6];
        float r2v = w0t[6] * win[4] + w0t[7] * win[5] + w0t[8] * win[6];
        // vertical scatter into circular accumulators (compile-time slots;
        // chunk starts are ≡ 0 mod 16 in local rows, so rr-based slots hold)
#pragma unroll
        for (int tt = 0; tt < 11; ++tt) acc[(rr + 5 - tt) & 15] += w12t[tt] * h11;
#pragma unroll
        for (int tt = 0; tt < 5; ++tt)  acc[(rr + 2 - tt) & 15] += w02t[tt] * h5;
        acc[(rr + 1) & 15]  += r0v;
        acc[rr & 15]        += r1v;
        acc[(rr + 15) & 15] += r2v;
        // output o_e = r0g+rr-5 is complete (or is warmup garbage: zero it).
        // o_e < oend is guaranteed for rr < rlim since lastrow <= oend+4.
        const int o_e = r0g + rr - 5;
        const int slot = (rr + 11) & 15;
        if (o_e >= obase)
          ebuf[rr][ch][xl] = (unsigned short)f2bf(acc[slot] + bias_row[ch][o_e - obase]);
        acc[slot] = 0.f;
      }
    }
    __syncthreads();
    // cooperative writeout: emitted o-rows, 16B per thread-pixel, contiguous
    for (int id = t; id < 512; id += 256) {
      int orr = id >> 5, x2 = id & 31;
      int o = r0g + orr - 5;
      if (orr < rlim && o >= obase) {
        unsigned u0 = ebuf[orr][0][x2] | ((unsigned)ebuf[orr][1][x2] << 16);
        unsigned u1 = ebuf[orr][2][x2] | ((unsigned)ebuf[orr][3][x2] << 16);
        unsigned u2 = ebuf[orr][4][x2] | ((unsigned)ebuf[orr][5][x2] << 16);
        unsigned u3 = ebuf[orr][6][x2] | ((unsigned)ebuf[orr][7][x2] << 16);
        uint4 pk; pk.x = u0; pk.y = u1; pk.z = u2; pk.w = u3;
        *(uint4*)(wsp + (size_t)(o * W_ + xbase + x2) * 8) = pk;
      }
    }
  }
  // drain outputs 123..127 (bottom y-block only; they complete at row 127)
  if (oend == H_) {
    __syncthreads();
#pragma unroll
    for (int orr = 0; orr < 5; ++orr) {
      const int o = H_ - 5 + orr;
      const int slot = (o - sbase) & 15;
      ebuf[orr][ch][xl] = (unsigned short)f2bf(acc[slot] + bias_row[ch][o - obase]);
    }
    __syncthreads();
    if (t < 160) {
      int orr = t >> 5, x2 = t & 31;
      int o = H_ - 5 + orr;
      unsigned u0 = ebuf[orr][0][x2] | ((unsigned)ebuf[orr][1][x2] << 16);
      unsigned u1 = ebuf[orr][2][x2] | ((unsigned)ebuf[orr][3][x2] << 16);
      unsigned u2 = ebuf[orr][4][x2] | ((unsigned)ebuf[orr][5][x2] << 16);
      unsigned u3 = ebuf[orr][6][x2] | ((unsigned)ebuf[orr][7][x2] << 16);
      uint4 pk; pk.x = u0; pk.y = u1; pk.z = u2; pk.w = u3;
      *(uint4*)(wsp + (size_t)(o * W_ + xbase + x2) * 8) = pk;
    }
  }
}

// ---------------------------------------------------------------------------
// Kernel 2: 1x1 channel mix via MFMA, A (=w3) resident in registers, no LDS.
// Wave w owns output channels [32w, 32w+32); block covers 64 pixels (4096
// blocks for parallelism). x loads hoisted ahead of the MFMA chain.
// ---------------------------------------------------------------------------
constexpr int PXB = 64;

__global__ __launch_bounds__(256, 4) void k_mix(
    const float* __restrict__ x,
    const float* __restrict__ w3, const float* __restrict__ b3,
    const unsigned short* __restrict__ ws,
    float* __restrict__ out)
{
  const int t = threadIdx.x;
  const int wv = t >> 6, lane = t & 63, q = lane >> 4, lp = lane & 15;
  const int n = blockIdx.y;
  const int px0 = blockIdx.x * PXB;

  // A fragments: rows o = 32*wv + 16*m + lp, k-slice ks*32 + q*8 (bf16-packed)
  s8v A[2][4];
  float b3v[2][4];
#pragma unroll
  for (int m = 0; m < 2; ++m) {
    const int o = 32 * wv + 16 * m + lp;
#pragma unroll
    for (int ks = 0; ks < 4; ++ks) {
      const float* src = w3 + o * 128 + ks * 32 + q * 8;
      float4 f0 = *(const float4*)src;
      float4 f1 = *(const float4*)(src + 4);
      union { s8v v; unsigned u[4]; } pk;
      pk.u[0] = f2bf(f0.x) | (f2bf(f0.y) << 16);
      pk.u[1] = f2bf(f0.z) | (f2bf(f0.w) << 16);
      pk.u[2] = f2bf(f1.x) | (f2bf(f1.y) << 16);
      pk.u[3] = f2bf(f1.z) | (f2bf(f1.w) << 16);
      A[m][ks] = pk.v;
    }
#pragma unroll
    for (int r = 0; r < 4; ++r) b3v[m][r] = b3[32 * wv + 16 * m + 4 * q + r];
  }

  const unsigned short* wsn = ws + (size_t)n * 16 * HW_ * 8;

#pragma unroll 2
  for (int npg = 0; npg < PXB / 16; ++npg) {
    const int pp = px0 + npg * 16 + lp;
    s8v B[4];
#pragma unroll
    for (int ks = 0; ks < 4; ++ks) {
      const int gg = ks * 4 + q;                 // channel-group for k = ks*32+q*8
      B[ks] = *(const s8v*)(wsn + ((size_t)gg * HW_ + pp) * 8);
    }
    // hoist the x (residual-multiply) loads so they overlap the MFMA chain
    float xv[2][4];
#pragma unroll
    for (int m = 0; m < 2; ++m)
#pragma unroll
      for (int r = 0; r < 4; ++r) {
        const int o = 32 * wv + 16 * m + 4 * q + r;
        xv[m][r] = x[((size_t)(n * C_ + o) << 14) + pp];
      }
    f4v acc[2] = {{0.f,0.f,0.f,0.f},{0.f,0.f,0.f,0.f}};
#pragma unroll
    for (int ks = 0; ks < 4; ++ks) {
#pragma unroll
      for (int m = 0; m < 2; ++m)
        acc[m] = __builtin_amdgcn_mfma_f32_16x16x32_bf16(A[m][ks], B[ks], acc[m], 0, 0, 0);
    }
#pragma unroll
    for (int m = 0; m < 2; ++m)
#pragma unroll
      for (int r = 0; r < 4; ++r) {
        const int o = 32 * wv + 16 * m + 4 * q + r;   // D row = q*4+r
        const size_t idx = ((size_t)(n * C_ + o) << 14) + pp;
        out[idx] = (acc[m][r] + b3v[m][r]) * xv[m][r];
      }
  }
}

extern "C" void kernel_launch(void* const* d_in, const int* in_sizes, int n_in,
                              void* d_out, int out_size, void* d_ws, size_t ws_size,
                              hipStream_t stream) {
  const float* x   = (const float*)d_in[0];
  const float* w0  = (const float*)d_in[1];
  const float* b0  = (const float*)d_in[2];
  const float* w01 = (const float*)d_in[3];
  const float* b01 = (const float*)d_in[4];
  const float* w02 = (const float*)d_in[5];
  const float* b02 = (const float*)d_in[6];
  const float* w11 = (const float*)d_in[7];
  const float* b11 = (const float*)d_in[8];
  const float* w12 = (const float*)d_in[9];
  const float* b12 = (const float*)d_in[10];
  const float* w3  = (const float*)d_in[11];
  const float* b3  = (const float*)d_in[12];
  unsigned short* ws = (unsigned short*)d_ws;   // 16*16*16384*8*2 = 64 MiB
  float* out = (float*)d_out;

  dim3 g1(4 * S_, 16, 16);   // (x-strips * y-splits, channel groups, batch)
  k_dw<<<g1, 256, 0, stream>>>(x, w0, b0, w01, b01, w02, b02, w11, b11, w12, b12, ws);

  dim3 g2(HW_ / PXB, 16);    // (64-px blocks, batch)
  k_mix<<<g2, 256, 0, stream>>>(x, w3, b3, ws, out);
}